// Round 10
// baseline (415.858 us; speedup 1.0000x reference)
//
#include <hip/hip_runtime.h>

// Heat equation, 2 materials, N=512, 499 steps, all frames written.
// Temporal tiling: K=16 steps/launch, 32 dispatches, 1024-thread blocks.
// R10: vertical slabs (wave = 4 rows x 64 cols, lane = column) + R9's
// nearest-neighbor wave-flag sync (no block barrier in the loop).
// Up/down interior = registers; left/right = DPP wave_shr/shl (VALU pipe);
// cross-wave traffic = 2 boundary floats/thread/step via LDS pairs.
// Boundary rows computed + published FIRST so neighbors unblock early;
// interior rows + global stores overlap. Frame stores fully async.

#define GN 512
#define NSTEPS 499
#define MBND 256
#define INV_DX2 261121.0f     // 511^2 = 1/dx^2
#define DT 5e-7f

#define TO 32                 // owned tile edge
#define KMAX 16               // steps per launch (= trapezoid margin)

// lane i <- lane i-1 (wave_shr:1); lane 0 keeps own value (junk-safe:
// region edge, outside validity trapezoid).
__device__ __forceinline__ float dpp_shr1(float x) {
    int v = __builtin_amdgcn_update_dpp(__float_as_int(x), __float_as_int(x),
                                        0x138, 0xf, 0xf, false);
    return __int_as_float(v);
}
// lane i <- lane i+1 (wave_shl:1)
__device__ __forceinline__ float dpp_shl1(float x) {
    int v = __builtin_amdgcn_update_dpp(__float_as_int(x), __float_as_int(x),
                                        0x130, 0xf, 0xf, false);
    return __int_as_float(v);
}

template<int STEPS>   // 16 (full) or 3 (tail)
__global__ __launch_bounds__(1024) void heat_multi(
    const float* __restrict__ Tin, float* __restrict__ outBase,
    const float* __restrict__ k1p, const float* __restrict__ k2p,
    const float* __restrict__ a1p, const float* __restrict__ a2p)
{
    // S[parity][wave slot w+1 (0,17 = never-written guards)][top/bot][col]
    __shared__ float S[2][18][2][64];
    __shared__ int fl[16];

    const int t    = threadIdx.x;            // 0..1023
    const int lane = t & 63;                 // column within 64-wide region
    const int w    = t >> 6;                 // wave id 0..15 (4 rows each)
    const int bi = blockIdx.x >> 4;          // 16x16 tile grid
    const int bj = blockIdx.x & 15;
    const int gi0 = bi * TO - KMAX;
    const int gj0 = bj * TO - KMAX;
    const int gj  = gj0 + lane;              // this thread's global column
    const int gr0 = gi0 + w * 4;             // first own global row

    const float k1 = k1p[0], k2 = k2p[0];
    const float a1 = a1p[0], a2 = a2p[0];
    const float invk = 1.0f / (k1 + k2);
    const float Ac = (DT * INV_DX2) * ((gj < MBND) ? a1 : a2);
    const bool ifcc = (gj == MBND - 1);
    const bool bcc  = (gj <= 0) || (gj >= GN - 1);
    bool br[4];
    #pragma unroll
    for (int r = 0; r < 4; ++r) {
        const int gi = gr0 + r;
        br[r] = (gi <= 0) || (gi >= GN - 1);
    }

    // block-uniform specialization (scalar branches)
    const bool aI = (bj == 7) || (bj == 8);
    const bool aC = (bj == 0) || (bj == 15);
    const bool aR = (bi == 0) || (bi == 15);

    // ---- initial state: rows gr0-1 .. gr0+4 straight from global (coalesced)
    const bool vc = ((unsigned)gj < GN);
    float R[4], tN, bN;
    #pragma unroll
    for (int r = 0; r < 4; ++r) {
        const int gi = gr0 + r;
        R[r] = (vc && (unsigned)gi < GN) ? Tin[(long)gi * GN + gj] : 0.0f;
    }
    { const int gi = gr0 - 1; tN = (vc && (unsigned)gi < GN) ? Tin[(long)gi * GN + gj] : 0.0f; }
    { const int gi = gr0 + 4; bN = (vc && (unsigned)gi < GN) ? Tin[(long)gi * GN + gj] : 0.0f; }

    if (t < 16) fl[t] = 0;                   // "state 0 published"
    __syncthreads();                         // the ONLY block-wide barrier

    const int wm1 = (w == 0) ? 0 : w - 1;    // w==0 waits on itself (always ok)
    const int wp1 = (w == 15) ? 15 : w + 1;

    const bool own = (w >= 4) && (w < 12) && (lane >= 16) && (lane < 48);
    float* d = outBase + ((long)gr0 * GN + gj);

    #pragma unroll
    for (int s = 1; s <= STEPS; ++s) {
        // 1) wait for neighbor waves to have published state s-1, then
        //    read ghost rows from parity buffer (s-1)&1.  s==1: ghosts
        //    already staged from global.
        if (s > 1) {
            while (__atomic_load_n(&fl[wm1], __ATOMIC_ACQUIRE) < s - 1 ||
                   __atomic_load_n(&fl[wp1], __ATOMIC_ACQUIRE) < s - 1)
                __builtin_amdgcn_s_sleep(1);
            const int rp = (s - 1) & 1;
            tN = S[rp][w][1][lane];          // wave w-1's row 3 (guard if w==0)
            bN = S[rp][w + 2][0][lane];      // wave w+1's row 0 (guard if w==15)
        }

        // 2) boundary rows first — they unblock the neighbors
        const float lf0 = dpp_shr1(R[0]), rt0 = dpp_shl1(R[0]);
        const float lf3 = dpp_shr1(R[3]), rt3 = dpp_shl1(R[3]);
        float N0 = fmaf(Ac, fmaf(-4.0f, R[0], (tN   + R[1]) + (lf0 + rt0)), R[0]);
        float N3 = fmaf(Ac, fmaf(-4.0f, R[3], (R[2] + bN  ) + (lf3 + rt3)), R[3]);
        if (aI) {        // interface column from OLD T neighbors
            N0 = ifcc ? (k1 * rt0 + k2 * lf0) * invk : N0;
            N3 = ifcc ? (k1 * rt3 + k2 * lf3) * invk : N3;
        }
        if (aC) { N0 = bcc ? 0.0f : N0;   N3 = bcc ? 0.0f : N3; }
        if (aR) { N0 = br[0] ? 0.0f : N0; N3 = br[3] ? 0.0f : N3; }

        // 3) publish + release flag (release orders the LDS data writes)
        if (s < STEPS) {
            const int wp = s & 1;
            S[wp][w + 1][0][lane] = N0;
            S[wp][w + 1][1][lane] = N3;
            if (lane == 0)
                __atomic_store_n(&fl[w], s, __ATOMIC_RELEASE);
        }

        // 4) interior rows: pure register compute (overlaps neighbors' reads)
        const float lf1 = dpp_shr1(R[1]), rt1 = dpp_shl1(R[1]);
        const float lf2 = dpp_shr1(R[2]), rt2 = dpp_shl1(R[2]);
        float N1 = fmaf(Ac, fmaf(-4.0f, R[1], (R[0] + R[2]) + (lf1 + rt1)), R[1]);
        float N2 = fmaf(Ac, fmaf(-4.0f, R[2], (R[1] + R[3]) + (lf2 + rt2)), R[2]);
        if (aI) {
            N1 = ifcc ? (k1 * rt1 + k2 * lf1) * invk : N1;
            N2 = ifcc ? (k1 * rt2 + k2 * lf2) * invk : N2;
        }
        if (aC) { N1 = bcc ? 0.0f : N1;   N2 = bcc ? 0.0f : N2; }
        if (aR) { N1 = br[1] ? 0.0f : N1; N2 = br[2] ? 0.0f : N2; }

        // 5) stream owned rows (async; nothing in the loop drains vmcnt)
        if (own) { d[0] = N0; d[GN] = N1; d[2 * GN] = N2; d[3 * GN] = N3; }
        d += (long)GN * GN;

        R[0] = N0; R[1] = N1; R[2] = N2; R[3] = N3;
    }
}

extern "C" void kernel_launch(void* const* d_in, const int* in_sizes, int n_in,
                              void* d_out, int out_size, void* d_ws, size_t ws_size,
                              hipStream_t stream)
{
    const float* u0 = (const float*)d_in[0];
    const float* k1 = (const float*)d_in[1];
    const float* k2 = (const float*)d_in[2];
    const float* a1 = (const float*)d_in[3];
    const float* a2 = (const float*)d_in[4];
    float* out = (float*)d_out;

    const int pts = GN * GN;
    const float* src = u0;
    int done = 0;
    while (done < NSTEPS) {
        int steps = NSTEPS - done;
        if (steps > KMAX) steps = KMAX;
        float* ob = out + (size_t)done * pts;
        if (steps == KMAX)
            heat_multi<KMAX><<<256, 1024, 0, stream>>>(src, ob, k1, k2, a1, a2);
        else  // NSTEPS = 31*16 + 3 -> remainder is always 3
            heat_multi<3><<<256, 1024, 0, stream>>>(src, ob, k1, k2, a1, a2);
        src = ob + (size_t)(steps - 1) * pts;
        done += steps;
    }
}